// Round 1
// baseline (234.383 us; speedup 1.0000x reference)
//
#include <hip/hip_runtime.h>

// Shift-and-Sum Quantizer.
// x:    [4,16,8192,64] fp32  (token = innermost 64-channel row)
// attn: [4,16,8192]    i32   (per-token level 0..3)
// out:  same shape as x, fp32
//
// Per token: M=max, m=min over 64 ch; delta=max((M-m)/255, 1e-6);
// zp=-rne(m/delta); v=x/delta.
//   level 0: xi = rne(v) + zp
//   level k: n=2^k; xi = (sum_i rne(v + (2i+1)/(2n)))/n + zp, i=-n/2..n/2-1
// out = (clip(xi,0,255) - zp) * delta
//
// Exactness notes: rne == jnp.round (banker's). IEEE '/' to match XLA fp32
// division bit-for-bit (quantization rounds are discontinuous; ulp drift near
// half-integers would cause O(delta) output mismatches). Shift-term sums are
// integer-valued fp32 -> exact regardless of order; /n is pow2 -> exact.

namespace {

constexpr int kThreads = 256;   // 4 waves/block
constexpr int kBlocks  = 2048;  // 8 blocks/CU on 256 CUs; grid-stride the rest

__global__ __launch_bounds__(kThreads) void ssq_kernel(
    const float* __restrict__ x,
    const int* __restrict__ attn,
    float* __restrict__ out,
    int n_quads)  // total float4 quads = n_elem/4; 16 quads per token
{
  const int stride = gridDim.x * kThreads;
  for (int q = blockIdx.x * kThreads + threadIdx.x; q < n_quads; q += stride) {
    const float4 xv = reinterpret_cast<const float4*>(x)[q];

    // --- per-token min/max: local over 4, then butterfly over the 16-lane
    // group that shares this token (xor masks 1,2,4,8 stay in-group).
    float lmin = fminf(fminf(xv.x, xv.y), fminf(xv.z, xv.w));
    float lmax = fmaxf(fmaxf(xv.x, xv.y), fmaxf(xv.z, xv.w));
    #pragma unroll
    for (int m = 1; m <= 8; m <<= 1) {
      lmin = fminf(lmin, __shfl_xor(lmin, m, 64));
      lmax = fmaxf(lmax, __shfl_xor(lmax, m, 64));
    }

    const float delta = fmaxf((lmax - lmin) / 255.0f, 1e-6f);
    const float zp    = -__builtin_rintf(lmin / delta);
    const int   a     = attn[q >> 4];  // uniform across the 16-lane group

    float v[4];
    v[0] = xv.x / delta;
    v[1] = xv.y / delta;
    v[2] = xv.z / delta;
    v[3] = xv.w / delta;

    float xi[4];
    if (a == 0) {
      #pragma unroll
      for (int e = 0; e < 4; ++e)
        xi[e] = __builtin_rintf(v[e]) + zp;
    } else if (a == 1) {
      #pragma unroll
      for (int e = 0; e < 4; ++e) {
        float acc = __builtin_rintf(v[e] - 0.25f)
                  + __builtin_rintf(v[e] + 0.25f);
        xi[e] = acc * 0.5f + zp;
      }
    } else if (a == 2) {
      #pragma unroll
      for (int e = 0; e < 4; ++e) {
        float acc = __builtin_rintf(v[e] - 0.375f)
                  + __builtin_rintf(v[e] - 0.125f)
                  + __builtin_rintf(v[e] + 0.125f)
                  + __builtin_rintf(v[e] + 0.375f);
        xi[e] = acc * 0.25f + zp;
      }
    } else {  // a == 3
      #pragma unroll
      for (int e = 0; e < 4; ++e) {
        float acc = __builtin_rintf(v[e] - 0.4375f)
                  + __builtin_rintf(v[e] - 0.3125f)
                  + __builtin_rintf(v[e] - 0.1875f)
                  + __builtin_rintf(v[e] - 0.0625f)
                  + __builtin_rintf(v[e] + 0.0625f)
                  + __builtin_rintf(v[e] + 0.1875f)
                  + __builtin_rintf(v[e] + 0.3125f)
                  + __builtin_rintf(v[e] + 0.4375f);
        xi[e] = acc * 0.125f + zp;
      }
    }

    float4 ov;
    float* ovp = &ov.x;
    #pragma unroll
    for (int e = 0; e < 4; ++e) {
      const float xq = fminf(fmaxf(xi[e], 0.0f), 255.0f);  // clip(xi,0,255)
      ovp[e] = (xq - zp) * delta;
    }
    reinterpret_cast<float4*>(out)[q] = ov;
  }
}

}  // namespace

extern "C" void kernel_launch(void* const* d_in, const int* in_sizes, int n_in,
                              void* d_out, int out_size, void* d_ws, size_t ws_size,
                              hipStream_t stream) {
  const float* x    = (const float*)d_in[0];
  const int*   attn = (const int*)d_in[1];
  float*       out  = (float*)d_out;

  const int n_quads = in_sizes[0] / 4;  // 8,388,608
  int blocks = (n_quads + kThreads - 1) / kThreads;
  if (blocks > kBlocks) blocks = kBlocks;

  ssq_kernel<<<blocks, kThreads, 0, stream>>>(x, attn, out, n_quads);
}

// Round 2
// 233.594 us; speedup vs baseline: 1.0034x; 1.0034x over previous
//
#include <hip/hip_runtime.h>

// Shift-and-Sum Quantizer — round 2.
// x:    [4,16,8192,64] fp32  (token = innermost 64-channel row)
// attn: [4,16,8192]    i32   (per-token level 0..3)
// out:  same shape, fp32
//
// Per token: M=max, m=min over 64 ch; delta=max((M-m)/255, 1e-6);
// zp=-rne(m/delta); v=x/delta.
//   level 0: xi = rne(v) + zp
//   level k: n=2^k; xi = (sum_i rne(v+(2i+1)/(2n)))/n + zp
//          == floor(n*v + 0.5)/n + zp       [Hermite: sum_j floor(y+j/n)=floor(ny);
//             differs from the reference only at fp-tie events, error <= delta/n]
// out = (clip(xi,0,255)-zp)*delta
//
// v = x/delta and m/delta use IEEE division (bit-exact vs XLA); n*v and /n are
// exact pow-2 scalings; +0.5 exact for |nv|<2^23.
//
// Min/max over the 16-lane token group via DPP butterflies (pure VALU, no LDS):
// quad_perm[1,0,3,2]=0xB1 (xor1), quad_perm[2,3,0,1]=0x4E (xor2),
// ROW_HALF_MIRROR=0x141 (crosses quads within 8), ROW_MIRROR=0x140 (crosses 8s).

namespace {

constexpr int kThreads = 256;   // 4 waves/block
constexpr int kBlocks  = 2048;  // 8192 waves = full residency on 256 CUs

template <int CTRL>
__device__ __forceinline__ float dppf(float x) {
  int xi = __builtin_bit_cast(int, x);
  return __builtin_bit_cast(
      float, __builtin_amdgcn_update_dpp(xi, xi, CTRL, 0xF, 0xF, false));
}

__device__ __forceinline__ float grp16_min(float v) {
  v = fminf(v, dppf<0xB1>(v));
  v = fminf(v, dppf<0x4E>(v));
  v = fminf(v, dppf<0x141>(v));
  v = fminf(v, dppf<0x140>(v));
  return v;
}
__device__ __forceinline__ float grp16_max(float v) {
  v = fmaxf(v, dppf<0xB1>(v));
  v = fmaxf(v, dppf<0x4E>(v));
  v = fmaxf(v, dppf<0x141>(v));
  v = fmaxf(v, dppf<0x140>(v));
  return v;
}

__global__ __launch_bounds__(kThreads) void ssq_kernel(
    const float* __restrict__ x,
    const int* __restrict__ attn,
    float* __restrict__ out,
    int n_quads)  // float4 quads; 16 quads (16 lanes) per token
{
  const int stride = gridDim.x * kThreads;
  for (int q = blockIdx.x * kThreads + threadIdx.x; q < n_quads; q += stride) {
    const float4 xv = reinterpret_cast<const float4*>(x)[q];

    float lmin = fminf(fminf(xv.x, xv.y), fminf(xv.z, xv.w));
    float lmax = fmaxf(fmaxf(xv.x, xv.y), fmaxf(xv.z, xv.w));
    lmin = grp16_min(lmin);
    lmax = grp16_max(lmax);

    const float delta = fmaxf((lmax - lmin) / 255.0f, 1e-6f);
    const float zp    = -__builtin_rintf(lmin / delta);

    const int   a  = attn[q >> 4];          // uniform across the 16-lane group
    const float s  = (float)(1 << a);       // 1,2,4,8  (exact)
    const float rs = __builtin_bit_cast(float, 0x3F800000 - (a << 23));  // 2^-a

    float vv[4] = {xv.x / delta, xv.y / delta, xv.z / delta, xv.w / delta};

    float4 ov;
    float* ovp = &ov.x;
    #pragma unroll
    for (int e = 0; e < 4; ++e) {
      const float v   = vv[e];
      const float xiN = __builtin_floorf(__builtin_fmaf(v, s, 0.5f)) * rs;
      const float xi0 = __builtin_rintf(v);
      const float xi  = ((a == 0) ? xi0 : xiN) + zp;
      const float xq  = fminf(fmaxf(xi, 0.0f), 255.0f);
      ovp[e] = (xq - zp) * delta;
    }
    reinterpret_cast<float4*>(out)[q] = ov;
  }
}

}  // namespace

extern "C" void kernel_launch(void* const* d_in, const int* in_sizes, int n_in,
                              void* d_out, int out_size, void* d_ws, size_t ws_size,
                              hipStream_t stream) {
  const float* x    = (const float*)d_in[0];
  const int*   attn = (const int*)d_in[1];
  float*       out  = (float*)d_out;

  const int n_quads = in_sizes[0] / 4;  // 8,388,608
  int blocks = (n_quads + kThreads - 1) / kThreads;
  if (blocks > kBlocks) blocks = kBlocks;

  ssq_kernel<<<blocks, kThreads, 0, stream>>>(x, attn, out, n_quads);
}

// Round 3
// 233.500 us; speedup vs baseline: 1.0038x; 1.0004x over previous
//
#include <hip/hip_runtime.h>

// Shift-and-Sum Quantizer — round 3: 4x unrolled, no grid-stride loop.
// x:    [4,16,8192,64] fp32  (token = innermost 64-channel row)
// attn: [4,16,8192]    i32   (per-token level 0..3)
// out:  same shape, fp32
//
// Math (per token): M,m over 64 ch; delta=max((M-m)/255,1e-6); zp=-rne(m/delta);
// v=x/delta; level 0: xi=rne(v)+zp; level k (n=2^k):
//   xi = (sum_i rne(v+(2i+1)/(2n)))/n + zp == floor(n*v+0.5)/n + zp
// (Hermite identity; differs from reference only at fp ties, |err|<=delta/n.)
// out = (clip(xi,0,255)-zp)*delta.
// IEEE '/' for x/delta, m/delta (bit-exact vs XLA); pow-2 scalings exact.
//
// Round-3 change: round 2 showed latency-bound (VALUBusy 38%, HBM 30%, VGPR=20
// -> one 1KB load in flight per wave, ~37% load duty cycle). Here each thread
// front-loads 4 independent quads (+4 attn words) -> 4x outstanding bytes and
// 4 independent compute chains for the scheduler to interleave.

namespace {

constexpr int kThreads = 256;   // 4 waves/block
constexpr int kUnroll  = 4;     // quads per thread
constexpr int kQPB     = kThreads * kUnroll;  // quads per block = 1024

template <int CTRL>
__device__ __forceinline__ float dppf(float x) {
  int xi = __builtin_bit_cast(int, x);
  return __builtin_bit_cast(
      float, __builtin_amdgcn_update_dpp(xi, xi, CTRL, 0xF, 0xF, false));
}

// min/max over the 16-lane token group: quad_perm xor1 (0xB1), xor2 (0x4E),
// ROW_HALF_MIRROR (0x141), ROW_MIRROR (0x140). Pure VALU, no LDS.
__device__ __forceinline__ float grp16_min(float v) {
  v = fminf(v, dppf<0xB1>(v));
  v = fminf(v, dppf<0x4E>(v));
  v = fminf(v, dppf<0x141>(v));
  v = fminf(v, dppf<0x140>(v));
  return v;
}
__device__ __forceinline__ float grp16_max(float v) {
  v = fmaxf(v, dppf<0xB1>(v));
  v = fmaxf(v, dppf<0x4E>(v));
  v = fmaxf(v, dppf<0x141>(v));
  v = fmaxf(v, dppf<0x140>(v));
  return v;
}

__global__ __launch_bounds__(kThreads, 8) void ssq_kernel(
    const float4* __restrict__ x,
    const int* __restrict__ attn,
    float4* __restrict__ out,
    int n_quads)
{
  const int base = blockIdx.x * kQPB + threadIdx.x;

  // Front-load everything: 4 independent x-quads + 4 attn words in flight.
  float4 xv[kUnroll];
  int    av[kUnroll];
  #pragma unroll
  for (int j = 0; j < kUnroll; ++j) {
    const int q = base + j * kThreads;
    if (q < n_quads) {
      xv[j] = x[q];
      av[j] = attn[q >> 4];   // uniform across each 16-lane token group
    }
  }

  #pragma unroll
  for (int j = 0; j < kUnroll; ++j) {
    const int q = base + j * kThreads;
    if (q >= n_quads) continue;
    const float4 v4 = xv[j];

    float lmin = fminf(fminf(v4.x, v4.y), fminf(v4.z, v4.w));
    float lmax = fmaxf(fmaxf(v4.x, v4.y), fmaxf(v4.z, v4.w));
    lmin = grp16_min(lmin);
    lmax = grp16_max(lmax);

    const float delta = fmaxf((lmax - lmin) / 255.0f, 1e-6f);
    const float zp    = -__builtin_rintf(lmin / delta);

    const int   a  = av[j];
    const float s  = (float)(1 << a);                                    // 2^a
    const float rs = __builtin_bit_cast(float, 0x3F800000 - (a << 23));  // 2^-a

    const float vv[4] = {v4.x / delta, v4.y / delta, v4.z / delta, v4.w / delta};

    float4 ov;
    float* ovp = &ov.x;
    #pragma unroll
    for (int e = 0; e < 4; ++e) {
      const float v   = vv[e];
      const float xiN = __builtin_floorf(__builtin_fmaf(v, s, 0.5f)) * rs;
      const float xi0 = __builtin_rintf(v);
      const float xi  = ((a == 0) ? xi0 : xiN) + zp;
      const float xq  = fminf(fmaxf(xi, 0.0f), 255.0f);
      ovp[e] = (xq - zp) * delta;
    }
    out[q] = ov;
  }
}

}  // namespace

extern "C" void kernel_launch(void* const* d_in, const int* in_sizes, int n_in,
                              void* d_out, int out_size, void* d_ws, size_t ws_size,
                              hipStream_t stream) {
  const float* x    = (const float*)d_in[0];
  const int*   attn = (const int*)d_in[1];
  float*       out  = (float*)d_out;

  const int n_quads = in_sizes[0] / 4;  // 8,388,608
  const int blocks  = (n_quads + kQPB - 1) / kQPB;  // 8192, exact cover

  ssq_kernel<<<blocks, kThreads, 0, stream>>>(
      reinterpret_cast<const float4*>(x), attn,
      reinterpret_cast<float4*>(out), n_quads);
}

// Round 7
// 232.210 us; speedup vs baseline: 1.0094x; 1.0056x over previous
//
#include <hip/hip_runtime.h>

// Shift-and-Sum Quantizer — round 7: identical to rounds 5/6 (both hit GPU
// acquisition timeouts; experiment still unbenchmarked). Experiment: force
// MLP with sched_barrier(0) + nontemporal stores.
//
// x:    [4,16,8192,64] fp32  (token = innermost 64-channel row)
// attn: [4,16,8192]    i32   (per-token level 0..3)
// out:  same shape, fp32
//
// Math (per token): M,m over 64 ch; delta=max((M-m)/255,1e-6); zp=-rne(m/delta);
// v=x/delta; level 0: xi=rne(v)+zp; level k (n=2^k):
//   xi = (sum_i rne(v+(2i+1)/(2n)))/n + zp == floor(n*v+0.5)/n + zp
// (Hermite identity; differs from reference only at fp ties, |err|<=delta/n.)
// out = (clip(xi,0,255)-zp)*delta.
// IEEE '/' for x/delta, m/delta (bit-exact vs XLA); pow-2 scalings exact.
//
// Experiment:
//  1. sched_barrier(0) between batched loads and compute — forbid load
//     sinking; keep 4 x-quads (4KB/wave) + attn in flight (vmcnt(6) at first
//     use instead of vmcnt(0)).
//  2. Exact-cover grid, no per-quad guards in the hot variant.
//  3. Nontemporal stores: out is never re-read; keep the 128MB write stream
//     from evicting x in L3 (expect FETCH_SIZE drop).

namespace {

constexpr int kThreads = 256;   // 4 waves/block
constexpr int kUnroll  = 4;     // quads per thread
constexpr int kQPB     = kThreads * kUnroll;  // 1024 quads per block

typedef float fvec4 __attribute__((ext_vector_type(4)));

template <int CTRL>
__device__ __forceinline__ float dppf(float x) {
  int xi = __builtin_bit_cast(int, x);
  return __builtin_bit_cast(
      float, __builtin_amdgcn_update_dpp(xi, xi, CTRL, 0xF, 0xF, false));
}

// min/max over the 16-lane token group: quad_perm xor1 (0xB1), xor2 (0x4E),
// ROW_HALF_MIRROR (0x141), ROW_MIRROR (0x140). Pure VALU, no LDS.
__device__ __forceinline__ float grp16_min(float v) {
  v = fminf(v, dppf<0xB1>(v));
  v = fminf(v, dppf<0x4E>(v));
  v = fminf(v, dppf<0x141>(v));
  v = fminf(v, dppf<0x140>(v));
  return v;
}
__device__ __forceinline__ float grp16_max(float v) {
  v = fmaxf(v, dppf<0xB1>(v));
  v = fmaxf(v, dppf<0x4E>(v));
  v = fmaxf(v, dppf<0x141>(v));
  v = fmaxf(v, dppf<0x140>(v));
  return v;
}

template <bool GUARD>
__global__ __launch_bounds__(kThreads, 8) void ssq_kernel(
    const fvec4* __restrict__ x,
    const int* __restrict__ attn,
    fvec4* __restrict__ out,
    int n_quads)
{
  const int base = blockIdx.x * kQPB + threadIdx.x;

  // Batch-issue all loads: 4 x-quads + 4 attn words in flight per thread.
  fvec4 xv[kUnroll];
  int   av[kUnroll];
  #pragma unroll
  for (int j = 0; j < kUnroll; ++j) {
    const int q = base + j * kThreads;
    if (!GUARD || q < n_quads) {
      xv[j] = x[q];
      av[j] = attn[q >> 4];  // uniform across each 16-lane token group
    }
  }
  // Hard scheduling fence: loads cannot sink below this point.
  __builtin_amdgcn_sched_barrier(0);

  #pragma unroll
  for (int j = 0; j < kUnroll; ++j) {
    const int q = base + j * kThreads;
    if (GUARD && q >= n_quads) continue;
    const fvec4 v4 = xv[j];

    float lmin = fminf(fminf(v4.x, v4.y), fminf(v4.z, v4.w));
    float lmax = fmaxf(fmaxf(v4.x, v4.y), fmaxf(v4.z, v4.w));
    lmin = grp16_min(lmin);
    lmax = grp16_max(lmax);

    const float delta = fmaxf((lmax - lmin) / 255.0f, 1e-6f);
    const float zp    = -__builtin_rintf(lmin / delta);

    const int   a  = av[j];
    const float s  = (float)(1 << a);                                    // 2^a
    const float rs = __builtin_bit_cast(float, 0x3F800000 - (a << 23));  // 2^-a

    const float vv[4] = {v4.x / delta, v4.y / delta, v4.z / delta, v4.w / delta};

    fvec4 ov;
    #pragma unroll
    for (int e = 0; e < 4; ++e) {
      const float v   = vv[e];
      const float xiN = __builtin_floorf(__builtin_fmaf(v, s, 0.5f)) * rs;
      const float xi0 = __builtin_rintf(v);
      const float xi  = ((a == 0) ? xi0 : xiN) + zp;
      const float xq  = fminf(fmaxf(xi, 0.0f), 255.0f);
      ov[e] = (xq - zp) * delta;
    }
    __builtin_nontemporal_store(ov, &out[q]);
  }
}

}  // namespace

extern "C" void kernel_launch(void* const* d_in, const int* in_sizes, int n_in,
                              void* d_out, int out_size, void* d_ws, size_t ws_size,
                              hipStream_t stream) {
  const float* x    = (const float*)d_in[0];
  const int*   attn = (const int*)d_in[1];
  float*       out  = (float*)d_out;

  const int n_quads = in_sizes[0] / 4;  // 8,388,608
  const int blocks  = (n_quads + kQPB - 1) / kQPB;

  if (n_quads % kQPB == 0) {
    ssq_kernel<false><<<blocks, kThreads, 0, stream>>>(
        reinterpret_cast<const fvec4*>(x), attn,
        reinterpret_cast<fvec4*>(out), n_quads);
  } else {
    ssq_kernel<true><<<blocks, kThreads, 0, stream>>>(
        reinterpret_cast<const fvec4*>(x), attn,
        reinterpret_cast<fvec4*>(out), n_quads);
  }
}